// Round 15
// baseline (140.338 us; speedup 1.0000x reference)
//
#include <hip/hip_runtime.h>
#include <hip/hip_fp16.h>

// Batched quantum-circuit sim — R14's instruction-count cuts with the
// register-cap lifted. R14 post-mortem: __launch_bounds__(256,2) CAPS the
// allocator at 128 VGPR (512/2/2); R14's coefficient arrays pushed demand
// to ~160 -> partial spill (VGPR=128 exactly, WRITE 4.6->15.4MB), eating
// the savings. But the grid supplies only 2 waves/SIMD (R13: more waves
// change nothing) and hardware runs 2/SIMD for ANY VGPR<=256 -> pressure
// in (128,256] is FREE. R15 = R14 + __launch_bounds__(256,1).
// Kept from R14 (both numerically exact):
//  1. Per-sim coefficient arrays computed once (kills R4's silent sincos
//     duplication: build+usweep recomputed identical values).
//  2. Depth loop fully unrolled (P1/P2 permutations = free renames in
//     straight-line SSA form).
// One launch, 256-thread blocks, one thread per element, single writer
// per output row (WRITE ideal at 4.6MB when spill-free).

#define DEVINL __device__ __forceinline__

typedef _Float16 hv2 __attribute__((ext_vector_type(2)));
typedef unsigned int u32;
typedef u32 vreg16 __attribute__((ext_vector_type(16)));
typedef u32 vreg64 __attribute__((ext_vector_type(64)));

struct C2 { __half2 rr, mp; };  // complex const (r,i): rr=(r,r), mp=(-i,+i)

DEVINL C2 mkc(float re, float im) {
  C2 c; c.rr = __floats2half2_rn(re, re); c.mp = __floats2half2_rn(-im, im); return c;
}
DEVINL __half2 mkamp(float re, float im) { return __floats2half2_rn(re, im); }
DEVINL __half2 swap2(__half2 v) { return __lowhigh2highlow(v); }
// (const u) * (amp v):  (r*vr - i*vi, r*vi + i*vr)
DEVINL __half2 cmulc(C2 u, __half2 v) { return __hfma2(u.rr, v, __hmul2(u.mp, swap2(v))); }

DEVINL float ampsq(__half2 v, float acc) {
#if __has_builtin(__builtin_amdgcn_fdot2)
  return __builtin_amdgcn_fdot2(__builtin_bit_cast(hv2, v), __builtin_bit_cast(hv2, v), acc, false);
#else
  float2 f = __half22float2(v);
  return fmaf(f.x, f.x, fmaf(f.y, f.y, acc));
#endif
}

constexpr int parc(int x) { x ^= x >> 4; x ^= x >> 2; x ^= x >> 1; return x & 1; }

struct c32 { float x, y; };
DEVINL c32 cmulf(c32 a, c32 b) { return { a.x*b.x - a.y*b.y, a.x*b.y + a.y*b.x }; }

// ---- SSA state accessors ----------------------------------------------------
template<class VT>
DEVINL __half2 vget(const VT& A, int i) { return __builtin_bit_cast(__half2, (u32)A[i]); }
template<class VT>
DEVINL void vset(VT& A, int i, __half2 v) { A[i] = __builtin_bit_cast(u32, v); }

// 128-amp state = two vreg64 tuples; index folds to constant after unroll.
struct S128 { vreg64 lo, hi; };
DEVINL __half2 vget(const S128& A, int i) {
  u32 u = (i < 64) ? (u32)A.lo[i] : (u32)A.hi[i - 64];
  return __builtin_bit_cast(__half2, u);
}
DEVINL void vset(S128& A, int i, __half2 v) {
  u32 u = __builtin_bit_cast(u32, v);
  if (i < 64) A.lo[i] = u; else A.hi[i - 64] = u;
}

// ---------------- generic gates (qubit W of N; mask = 1<<(N-1-W)) -----------

template<int N, int W, class VT>
DEVINL void g_ry(VT& A, __half2 c2, __half2 s2, __half2 ns2) {
  constexpr int M = 1 << (N - 1 - W);
#pragma unroll
  for (int i = 0; i < (1 << N); ++i) if (!(i & M)) {
    const int j = i | M;
    __half2 v0 = vget(A, i), v1 = vget(A, j);
    vset(A, i, __hfma2(c2, v0, __hmul2(ns2, v1)));
    vset(A, j, __hfma2(c2, v1, __hmul2(s2, v0)));
  }
}

template<int N, int W, class VT>
DEVINL void g_u2(VT& A, C2 u00, C2 u01, C2 u10, C2 u11) {
  constexpr int M = 1 << (N - 1 - W);
#pragma unroll
  for (int i = 0; i < (1 << N); ++i) if (!(i & M)) {
    const int j = i | M;
    __half2 v0 = vget(A, i), v1 = vget(A, j), v0s = swap2(v0), v1s = swap2(v1);
    vset(A, i, __hfma2(u00.rr, v0, __hfma2(u00.mp, v0s, __hfma2(u01.rr, v1, __hmul2(u01.mp, v1s)))));
    vset(A, j, __hfma2(u10.rr, v0, __hfma2(u10.mp, v0s, __hfma2(u11.rr, v1, __hmul2(u11.mp, v1s)))));
  }
}

template<int N, int C, int T, class VT>
DEVINL void g_cnot(VT& A) {
  constexpr int CM = 1 << (N - 1 - C), TM = 1 << (N - 1 - T);
#pragma unroll
  for (int i = 0; i < (1 << N); ++i) if ((i & CM) && !(i & TM)) {
    const int j = i | TM;
    __half2 t = vget(A, i); vset(A, i, vget(A, j)); vset(A, j, t);
  }
}

template<int N, int K, class VT>
DEVINL void chain_cnot(VT& A) {
  if constexpr (K < N - 1) { g_cnot<N, K, K + 1>(A); chain_cnot<N, K + 1>(A); }
}

// ---------------- per-qubit coefficients (f32) ------------------------------
// forward: u = Rz(phi)Ry(pt)Rx(eta)|0>;  reverse merged: U = Rx(phi)Ry(pt)Rz(eta)

DEVINL void mk_u01(float ce, float se, float cp, float sp, float cf, float sf,
                   c32& u0, c32& u1) {
  u0 = cmulf({cf, -sf}, {cp * ce, sp * se});
  u1 = cmulf({cf,  sf}, {sp * ce, -cp * se});
}

DEVINL void mk_U(float ce, float se, float cp, float sp, float cf, float sf,
                 C2& U00, C2& U01, C2& U10, C2& U11) {
  c32 z = {ce, -se}, zb = {ce, se};
  c32 A = cmulf({cf * cp, -sf * sp}, z);
  c32 T = cmulf({cf * sp,  sf * cp}, zb);
  c32 Cc = cmulf({cf * sp, -sf * cp}, z);
  c32 D = cmulf({cf * cp,  sf * sp}, zb);
  U00 = mkc(A.x, A.y); U01 = mkc(-T.x, -T.y); U10 = mkc(Cc.x, Cc.y); U11 = mkc(D.x, D.y);
}

// product state build by doubling (A[0] must be (1,0) on entry).
// step M's qubit lands at bit (N-1-M). CF(M,u0,u1) supplies the column.
template<int N, int M, class VT, class CF>
DEVINL void build_rec(VT& A, CF cf) {
  if constexpr (M < N) {
    c32 u0, u1; cf(M, u0, u1);
    C2 c0 = mkc(u0.x, u0.y), c1 = mkc(u1.x, u1.y);
#pragma unroll
    for (int j = (1 << M) - 1; j >= 0; --j) {
      __half2 s = vget(A, j);
      vset(A, 2 * j,     cmulc(c0, s));
      vset(A, 2 * j + 1, cmulc(c1, s));
    }
    build_rec<N, M + 1>(A, cf);
  }
}

template<int N, int K, class VT, class CF>
DEVINL void usweep_rec(VT& A, CF cf) {
  if constexpr (K < N) {
    C2 U00, U01, U10, U11;
    cf(K, U00, U01, U10, U11);
    g_u2<N, K>(A, U00, U01, U10, U11);
    usweep_rec<N, K + 1>(A, cf);
  }
}

template<int N, int K, class VT, class CF>
DEVINL void ry_rec(VT& A, CF cf) {
  if constexpr (K < N) {
    __half2 c2, s2, ns2;
    cf(K, c2, s2, ns2);
    g_ry<N, K>(A, c2, s2, ns2);
    ry_rec<N, K + 1>(A, cf);
  }
}

// ---------------- 4-qubit block I (verified math, SSA state) ----------------
// Coefficients computed ONCE into small arrays (indices fold to constants
// after inlining -> SROA-promoted), reused by build and usweep.

template<int I>
DEVINL void sim4h(const float* __restrict__ xr, const float* __restrict__ w, float* z) {
  constexpr int PT[3][4]  = {{5, 4, 35, 34}, {3, 33, 31, 2}, {28, 32, 15, 16}};
  constexpr int ETA[3][4] = {{9, 8, 45, 44}, {7, 43, 41, 6}, {38, 42, 19, 20}};
  constexpr int PHI[3][4] = {{13, 12, 55, 54}, {11, 53, 51, 10}, {48, 52, 23, 24}};
  float ce[4], se[4], cp[4], sp[4], cf[4], sf[4];
#pragma unroll
  for (int k = 0; k < 4; ++k) {
    __sincosf(0.5f * xr[ETA[I][k]], &se[k], &ce[k]);
    __sincosf(0.5f * xr[PT[I][k]],  &sp[k], &cp[k]);
    __sincosf(0.5f * xr[PHI[I][k]], &sf[k], &cf[k]);
  }
  vreg16 A;
  vset(A, 0, mkamp(1.f, 0.f));
  build_rec<4, 0>(A, [&](int M, c32& u0, c32& u1) {
    mk_u01(ce[M], se[M], cp[M], sp[M], cf[M], sf[M], u0, u1);
  });
  chain_cnot<4, 0>(A);
  usweep_rec<4, 0>(A, [&](int K, C2& U00, C2& U01, C2& U10, C2& U11) {
    mk_U(ce[K], se[K], cp[K], sp[K], cf[K], sf[K], U00, U01, U10, U11);
  });

  // t->l CNOT block == flip q0,q1 (mask 12) iff parity(b2,b3) (i&3)
#pragma unroll
  for (int i = 0; i < 16; ++i)
    if (parc(i & 3) && !(i & 8)) {
      __half2 t = vget(A, i); vset(A, i, vget(A, i ^ 12)); vset(A, i ^ 12, t);
    }

  ry_rec<4, 0>(A, [&](int K, __half2& c2, __half2& s2, __half2& ns2) {
    float sv, cv; __sincosf(0.5f * w[K], &sv, &cv);
    c2 = __floats2half2_rn(cv, cv);
    s2 = __floats2half2_rn(sv, sv);
    ns2 = __floats2half2_rn(-sv, -sv);
  });

  // l->t CNOT block == flip q2,q3 (mask 3) iff parity(b0,b1) (i&12)
#pragma unroll
  for (int i = 0; i < 16; ++i)
    if (parc(i & 12) && !(i & 2)) {
      __half2 t = vget(A, i); vset(A, i, vget(A, i ^ 3)); vset(A, i ^ 3, t);
    }

  float cls[4];
#pragma unroll
  for (int c = 0; c < 4; ++c) cls[c] = 0.f;
#pragma unroll
  for (int i = 0; i < 16; ++i) cls[i & 3] = ampsq(vget(A, i), cls[i & 3]);
  float z0 = 0.f, z1 = 0.f;
#pragma unroll
  for (int c = 0; c < 4; ++c) {
    z0 += (c & 2) ? -cls[c] : cls[c];
    z1 += (c & 1) ? -cls[c] : cls[c];
  }
  z[0] = z0; z[1] = z1;
}

// ---------------- 7-qubit block (verified math, S128 SSA state) -------------
// qubit k at bit 6-k. latent=(0..3) trash=(4,5,6) depth=4.

DEVINL void sim7(const float* __restrict__ xr, const float* __restrict__ wD,
                 float* z) {
  constexpr int PT[7]  = {0, 14, 30, 26, 29, 27, 17};
  constexpr int ETA[7] = {-1, 18, 40, 36, 39, 37, 21};  // -1 -> zeros (None)
  constexpr int PHI[7] = {1, 22, 50, 46, 49, 47, 25};

  float ce[7], se[7], cp[7], sp[7], cf[7], sf[7];
#pragma unroll
  for (int k = 0; k < 7; ++k) {
    float e = (ETA[k] < 0) ? 0.f : xr[ETA[k]];
    __sincosf(0.5f * e, &se[k], &ce[k]);
    __sincosf(0.5f * xr[PT[k]],  &sp[k], &cp[k]);
    __sincosf(0.5f * xr[PHI[k]], &sf[k], &cf[k]);
  }

  S128 A;
  vset(A, 0, mkamp(1.f, 0.f));
  build_rec<7, 0>(A, [&](int M, c32& u0, c32& u1) {
    mk_u01(ce[M], se[M], cp[M], sp[M], cf[M], sf[M], u0, u1);
  });
  chain_cnot<7, 0>(A);
  usweep_rec<7, 0>(A, [&](int K, C2& U00, C2& U01, C2& U10, C2& U11) {
    mk_U(ce[K], se[K], cp[K], sp[K], cf[K], sf[K], U00, U01, U10, U11);
  });

  // depth loop FULLY unrolled: P1/P2 permutations become compile-time
  // renames in straight-line SSA form.
#pragma unroll
  for (int d = 0; d < 4; ++d) {
    // t->l block == flip q0..q3 (mask 0x78) iff parity(q4,q5,q6) (i&7)
#pragma unroll
    for (int i = 0; i < 128; ++i)
      if (parc(i & 7) && !(i & 64)) {
        __half2 t = vget(A, i); vset(A, i, vget(A, i ^ 0x78)); vset(A, i ^ 0x78, t);
      }

    ry_rec<7, 0>(A, [&](int K, __half2& c2, __half2& s2, __half2& ns2) {
      float sv, cv; __sincosf(0.5f * wD[7 * d + K], &sv, &cv);
      c2 = __floats2half2_rn(cv, cv);
      s2 = __floats2half2_rn(sv, sv);
      ns2 = __floats2half2_rn(-sv, -sv);
    });

    // l->t block == flip q4..q6 (mask 7) iff parity(q0..q3) (i&0x78)
#pragma unroll
    for (int i = 0; i < 128; ++i)
      if (parc(i & 0x78) && !(i & 4)) {
        __half2 t = vget(A, i); vset(A, i, vget(A, i ^ 7)); vset(A, i ^ 7, t);
      }
  }

  float cls[8];
#pragma unroll
  for (int c = 0; c < 8; ++c) cls[c] = 0.f;
#pragma unroll
  for (int i = 0; i < 128; ++i) cls[i & 7] = ampsq(vget(A, i), cls[i & 7]);
  float z4 = 0.f, z5 = 0.f, z6 = 0.f;
#pragma unroll
  for (int c = 0; c < 8; ++c) {
    z4 += (c & 4) ? -cls[c] : cls[c];
    z5 += (c & 2) ? -cls[c] : cls[c];
    z6 += (c & 1) ? -cls[c] : cls[c];
  }
  z[0] = z4; z[1] = z5; z[2] = z6;
}

// ---------------- fused kernel: one thread per element ----------------------
// launch_bounds(256,1): allocator may use up to 256 VGPR. Grid supplies only
// 2 waves/SIMD and HW runs 2/SIMD for any VGPR<=256, so pressure in
// (128,256] is free; the (256,2) cap was forcing R14's spill.

__global__ void __launch_bounds__(256, 1)
k_all(const float* __restrict__ x,
      const float* __restrict__ wA, const float* __restrict__ wB,
      const float* __restrict__ wC, const float* __restrict__ wD,
      float* __restrict__ out, int B) {
  const int b = blockIdx.x * 256 + threadIdx.x;
  if (b >= B) return;
  const float* xr = x + (size_t)b * 56;

  float o[9];
  // ABC first: vreg16 state is dead before the 128-reg 7q state allocates.
  sim4h<0>(xr, wA, &o[0]);
  sim4h<1>(xr, wB, &o[2]);
  sim4h<2>(xr, wC, &o[4]);
  sim7(xr, wD, &o[6]);

  float* op = out + (size_t)b * 9;
#pragma unroll
  for (int i = 0; i < 9; ++i) op[i] = o[i];
}

// ---------------- launch ----------------------------------------------------

extern "C" void kernel_launch(void* const* d_in, const int* in_sizes, int n_in,
                              void* d_out, int out_size, void* d_ws, size_t ws_size,
                              hipStream_t stream) {
  const float* x  = (const float*)d_in[0];
  const float* wA = (const float*)d_in[1];
  const float* wB = (const float*)d_in[2];
  const float* wC = (const float*)d_in[3];
  const float* wD = (const float*)d_in[4];
  float* out = (float*)d_out;
  const int B = in_sizes[0] / 56;
  const int threads = 256;

  const int blocks = (B + threads - 1) / threads;
  k_all<<<blocks, threads, 0, stream>>>(x, wA, wB, wC, wD, out, B);
}

// Round 16
// 133.975 us; speedup vs baseline: 1.0475x; 1.0475x over previous
//
#include <hip/hip_runtime.h>
#include <hip/hip_fp16.h>

// Batched quantum-circuit sim — R12 configuration EXACTLY (the empirical
// optimum: 66.4us dispatch, WRITE ideal 4.6MB, VGPR 120, rolled depth
// loop, point-of-use sincos, S128 SSA state, launch_bounds(256,2)) with
// ONE change: the three sim4h<I> template instantiations are collapsed
// into a single __noinline__ function called 3x with a runtime column
// index. Executed instructions unchanged; CODE FOOTPRINT of the ABC
// phase shrinks ~3x (~20KB) to relieve L1I (32KB/CU) streaming pressure
// — the baseline author's "body stays in L1I" note says I-fetch matters
// here, and R14/R15 proved code-size growth regresses (66->72->81us).
// Diagnostic: dur drops -> I-fetch was part of the ~30% non-VALU stall;
// dur neutral -> R12 is the VALU-issue floor.

#define DEVINL __device__ __forceinline__

typedef _Float16 hv2 __attribute__((ext_vector_type(2)));
typedef unsigned int u32;
typedef u32 vreg16 __attribute__((ext_vector_type(16)));
typedef u32 vreg64 __attribute__((ext_vector_type(64)));

struct C2 { __half2 rr, mp; };  // complex const (r,i): rr=(r,r), mp=(-i,+i)

DEVINL C2 mkc(float re, float im) {
  C2 c; c.rr = __floats2half2_rn(re, re); c.mp = __floats2half2_rn(-im, im); return c;
}
DEVINL __half2 mkamp(float re, float im) { return __floats2half2_rn(re, im); }
DEVINL __half2 swap2(__half2 v) { return __lowhigh2highlow(v); }
// (const u) * (amp v):  (r*vr - i*vi, r*vi + i*vr)
DEVINL __half2 cmulc(C2 u, __half2 v) { return __hfma2(u.rr, v, __hmul2(u.mp, swap2(v))); }

DEVINL float ampsq(__half2 v, float acc) {
#if __has_builtin(__builtin_amdgcn_fdot2)
  return __builtin_amdgcn_fdot2(__builtin_bit_cast(hv2, v), __builtin_bit_cast(hv2, v), acc, false);
#else
  float2 f = __half22float2(v);
  return fmaf(f.x, f.x, fmaf(f.y, f.y, acc));
#endif
}

constexpr int parc(int x) { x ^= x >> 4; x ^= x >> 2; x ^= x >> 1; return x & 1; }

struct c32 { float x, y; };
DEVINL c32 cmulf(c32 a, c32 b) { return { a.x*b.x - a.y*b.y, a.x*b.y + a.y*b.x }; }

// ---- SSA state accessors ----------------------------------------------------
template<class VT>
DEVINL __half2 vget(const VT& A, int i) { return __builtin_bit_cast(__half2, (u32)A[i]); }
template<class VT>
DEVINL void vset(VT& A, int i, __half2 v) { A[i] = __builtin_bit_cast(u32, v); }

// 128-amp state = two vreg64 tuples; index folds to constant after unroll.
struct S128 { vreg64 lo, hi; };
DEVINL __half2 vget(const S128& A, int i) {
  u32 u = (i < 64) ? (u32)A.lo[i] : (u32)A.hi[i - 64];
  return __builtin_bit_cast(__half2, u);
}
DEVINL void vset(S128& A, int i, __half2 v) {
  u32 u = __builtin_bit_cast(u32, v);
  if (i < 64) A.lo[i] = u; else A.hi[i - 64] = u;
}

// ---------------- generic gates (qubit W of N; mask = 1<<(N-1-W)) -----------

template<int N, int W, class VT>
DEVINL void g_ry(VT& A, __half2 c2, __half2 s2, __half2 ns2) {
  constexpr int M = 1 << (N - 1 - W);
#pragma unroll
  for (int i = 0; i < (1 << N); ++i) if (!(i & M)) {
    const int j = i | M;
    __half2 v0 = vget(A, i), v1 = vget(A, j);
    vset(A, i, __hfma2(c2, v0, __hmul2(ns2, v1)));
    vset(A, j, __hfma2(c2, v1, __hmul2(s2, v0)));
  }
}

template<int N, int W, class VT>
DEVINL void g_u2(VT& A, C2 u00, C2 u01, C2 u10, C2 u11) {
  constexpr int M = 1 << (N - 1 - W);
#pragma unroll
  for (int i = 0; i < (1 << N); ++i) if (!(i & M)) {
    const int j = i | M;
    __half2 v0 = vget(A, i), v1 = vget(A, j), v0s = swap2(v0), v1s = swap2(v1);
    vset(A, i, __hfma2(u00.rr, v0, __hfma2(u00.mp, v0s, __hfma2(u01.rr, v1, __hmul2(u01.mp, v1s)))));
    vset(A, j, __hfma2(u10.rr, v0, __hfma2(u10.mp, v0s, __hfma2(u11.rr, v1, __hmul2(u11.mp, v1s)))));
  }
}

template<int N, int C, int T, class VT>
DEVINL void g_cnot(VT& A) {
  constexpr int CM = 1 << (N - 1 - C), TM = 1 << (N - 1 - T);
#pragma unroll
  for (int i = 0; i < (1 << N); ++i) if ((i & CM) && !(i & TM)) {
    const int j = i | TM;
    __half2 t = vget(A, i); vset(A, i, vget(A, j)); vset(A, j, t);
  }
}

template<int N, int K, class VT>
DEVINL void chain_cnot(VT& A) {
  if constexpr (K < N - 1) { g_cnot<N, K, K + 1>(A); chain_cnot<N, K + 1>(A); }
}

// ---------------- per-qubit coefficients (f32) ------------------------------
// forward: u = Rz(phi)Ry(pt)Rx(eta)|0>;  reverse merged: U = Rx(phi)Ry(pt)Rz(eta)

DEVINL void mk_u01(float ce, float se, float cp, float sp, float cf, float sf,
                   c32& u0, c32& u1) {
  u0 = cmulf({cf, -sf}, {cp * ce, sp * se});
  u1 = cmulf({cf,  sf}, {sp * ce, -cp * se});
}

DEVINL void mk_U(float ce, float se, float cp, float sp, float cf, float sf,
                 C2& U00, C2& U01, C2& U10, C2& U11) {
  c32 z = {ce, -se}, zb = {ce, se};
  c32 A = cmulf({cf * cp, -sf * sp}, z);
  c32 T = cmulf({cf * sp,  sf * cp}, zb);
  c32 Cc = cmulf({cf * sp, -sf * cp}, z);
  c32 D = cmulf({cf * cp,  sf * sp}, zb);
  U00 = mkc(A.x, A.y); U01 = mkc(-T.x, -T.y); U10 = mkc(Cc.x, Cc.y); U11 = mkc(D.x, D.y);
}

// per-qubit sincos loader (eta_i<0 -> eta=0)
DEVINL void load_sc(const float* __restrict__ xr, int eta_i, int pt_i, int phi_i,
                    float& ce, float& se, float& cp, float& sp, float& cf, float& sf) {
  float e = (eta_i < 0) ? 0.f : xr[eta_i];
  __sincosf(0.5f * e, &se, &ce);
  __sincosf(0.5f * xr[pt_i], &sp, &cp);
  __sincosf(0.5f * xr[phi_i], &sf, &cf);
}

// product state build by doubling (A[0] must be (1,0) on entry).
// step M's qubit lands at bit (N-1-M). CF(M,u0,u1) supplies the column.
template<int N, int M, class VT, class CF>
DEVINL void build_rec(VT& A, CF cf) {
  if constexpr (M < N) {
    c32 u0, u1; cf(M, u0, u1);
    C2 c0 = mkc(u0.x, u0.y), c1 = mkc(u1.x, u1.y);
#pragma unroll
    for (int j = (1 << M) - 1; j >= 0; --j) {
      __half2 s = vget(A, j);
      vset(A, 2 * j,     cmulc(c0, s));
      vset(A, 2 * j + 1, cmulc(c1, s));
    }
    build_rec<N, M + 1>(A, cf);
  }
}

template<int N, int K, class VT, class CF>
DEVINL void usweep_rec(VT& A, CF cf) {
  if constexpr (K < N) {
    C2 U00, U01, U10, U11;
    cf(K, U00, U01, U10, U11);
    g_u2<N, K>(A, U00, U01, U10, U11);
    usweep_rec<N, K + 1>(A, cf);
  }
}

template<int N, int K, class VT, class CF>
DEVINL void ry_rec(VT& A, CF cf) {
  if constexpr (K < N) {
    __half2 c2, s2, ns2;
    cf(K, c2, s2, ns2);
    g_ry<N, K>(A, c2, s2, ns2);
    ry_rec<N, K + 1>(A, cf);
  }
}

// ---------------- 4-qubit block, ONE shared copy (noinline) -----------------
// Runtime column index I (0..2) selects the input columns from .rodata
// tables; state indices inside remain compile-time (full unroll).
// R12 math byte-identical; only the instantiation strategy changed.

__device__ __noinline__ void sim4h_rt(const float* __restrict__ xr,
                                      const float* __restrict__ w, int I,
                                      float* z) {
  static const int PT[3][4]  = {{5, 4, 35, 34}, {3, 33, 31, 2}, {28, 32, 15, 16}};
  static const int ETA[3][4] = {{9, 8, 45, 44}, {7, 43, 41, 6}, {38, 42, 19, 20}};
  static const int PHI[3][4] = {{13, 12, 55, 54}, {11, 53, 51, 10}, {48, 52, 23, 24}};
  vreg16 A;
  vset(A, 0, mkamp(1.f, 0.f));
  build_rec<4, 0>(A, [&](int M, c32& u0, c32& u1) {
    float ce, se, cp, sp, cf, sf;
    load_sc(xr, ETA[I][M], PT[I][M], PHI[I][M], ce, se, cp, sp, cf, sf);
    mk_u01(ce, se, cp, sp, cf, sf, u0, u1);
  });
  chain_cnot<4, 0>(A);
  usweep_rec<4, 0>(A, [&](int K, C2& U00, C2& U01, C2& U10, C2& U11) {
    float ce, se, cp, sp, cf, sf;
    load_sc(xr, ETA[I][K], PT[I][K], PHI[I][K], ce, se, cp, sp, cf, sf);
    mk_U(ce, se, cp, sp, cf, sf, U00, U01, U10, U11);
  });

  // t->l CNOT block == flip q0,q1 (mask 12) iff parity(b2,b3) (i&3)
#pragma unroll
  for (int i = 0; i < 16; ++i)
    if (parc(i & 3) && !(i & 8)) {
      __half2 t = vget(A, i); vset(A, i, vget(A, i ^ 12)); vset(A, i ^ 12, t);
    }

  ry_rec<4, 0>(A, [&](int K, __half2& c2, __half2& s2, __half2& ns2) {
    float sv, cv; __sincosf(0.5f * w[K], &sv, &cv);
    c2 = __floats2half2_rn(cv, cv);
    s2 = __floats2half2_rn(sv, sv);
    ns2 = __floats2half2_rn(-sv, -sv);
  });

  // l->t CNOT block == flip q2,q3 (mask 3) iff parity(b0,b1) (i&12)
#pragma unroll
  for (int i = 0; i < 16; ++i)
    if (parc(i & 12) && !(i & 2)) {
      __half2 t = vget(A, i); vset(A, i, vget(A, i ^ 3)); vset(A, i ^ 3, t);
    }

  float cls[4];
#pragma unroll
  for (int c = 0; c < 4; ++c) cls[c] = 0.f;
#pragma unroll
  for (int i = 0; i < 16; ++i) cls[i & 3] = ampsq(vget(A, i), cls[i & 3]);
  float z0 = 0.f, z1 = 0.f;
#pragma unroll
  for (int c = 0; c < 4; ++c) {
    z0 += (c & 2) ? -cls[c] : cls[c];
    z1 += (c & 1) ? -cls[c] : cls[c];
  }
  z[0] = z0; z[1] = z1;
}

// ---------------- 7-qubit block (R12-verified math, S128 SSA state) ---------
// qubit k at bit 6-k. latent=(0..3) trash=(4,5,6) depth=4.

DEVINL void sim7(const float* __restrict__ xr, const float* __restrict__ wD,
                 float* z) {
  constexpr int PT[7]  = {0, 14, 30, 26, 29, 27, 17};
  constexpr int ETA[7] = {-1, 18, 40, 36, 39, 37, 21};  // -1 -> zeros (None)
  constexpr int PHI[7] = {1, 22, 50, 46, 49, 47, 25};

  S128 A;
  vset(A, 0, mkamp(1.f, 0.f));
  build_rec<7, 0>(A, [&](int M, c32& u0, c32& u1) {
    float ce, se, cp, sp, cf, sf;
    load_sc(xr, ETA[M], PT[M], PHI[M], ce, se, cp, sp, cf, sf);
    mk_u01(ce, se, cp, sp, cf, sf, u0, u1);
  });
  chain_cnot<7, 0>(A);
  usweep_rec<7, 0>(A, [&](int K, C2& U00, C2& U01, C2& U10, C2& U11) {
    float ce, se, cp, sp, cf, sf;
    load_sc(xr, ETA[K], PT[K], PHI[K], ce, se, cp, sp, cf, sf);
    mk_U(ce, se, cp, sp, cf, sf, U00, U01, U10, U11);
  });

  // depth loop kept rolled: body stays in L1I
#pragma unroll 1
  for (int d = 0; d < 4; ++d) {
    // t->l block == flip q0..q3 (mask 0x78) iff parity(q4,q5,q6) (i&7)
#pragma unroll
    for (int i = 0; i < 128; ++i)
      if (parc(i & 7) && !(i & 64)) {
        __half2 t = vget(A, i); vset(A, i, vget(A, i ^ 0x78)); vset(A, i ^ 0x78, t);
      }

    ry_rec<7, 0>(A, [&](int K, __half2& c2, __half2& s2, __half2& ns2) {
      float sv, cv; __sincosf(0.5f * wD[7 * d + K], &sv, &cv);
      c2 = __floats2half2_rn(cv, cv);
      s2 = __floats2half2_rn(sv, sv);
      ns2 = __floats2half2_rn(-sv, -sv);
    });

    // l->t block == flip q4..q6 (mask 7) iff parity(q0..q3) (i&0x78)
#pragma unroll
    for (int i = 0; i < 128; ++i)
      if (parc(i & 0x78) && !(i & 4)) {
        __half2 t = vget(A, i); vset(A, i, vget(A, i ^ 7)); vset(A, i ^ 7, t);
      }
  }

  float cls[8];
#pragma unroll
  for (int c = 0; c < 8; ++c) cls[c] = 0.f;
#pragma unroll
  for (int i = 0; i < 128; ++i) cls[i & 7] = ampsq(vget(A, i), cls[i & 7]);
  float z4 = 0.f, z5 = 0.f, z6 = 0.f;
#pragma unroll
  for (int c = 0; c < 8; ++c) {
    z4 += (c & 4) ? -cls[c] : cls[c];
    z5 += (c & 2) ? -cls[c] : cls[c];
    z6 += (c & 1) ? -cls[c] : cls[c];
  }
  z[0] = z4; z[1] = z5; z[2] = z6;
}

// ---------------- fused kernel: one thread per element ----------------------

__global__ void __launch_bounds__(256, 2)
k_all(const float* __restrict__ x,
      const float* __restrict__ wA, const float* __restrict__ wB,
      const float* __restrict__ wC, const float* __restrict__ wD,
      float* __restrict__ out, int B) {
  const int b = blockIdx.x * 256 + threadIdx.x;
  if (b >= B) return;
  const float* xr = x + (size_t)b * 56;

  float o[9];
  // ABC via ONE shared noinline body (3 calls): ~3x smaller I-footprint.
  sim4h_rt(xr, wA, 0, &o[0]);
  sim4h_rt(xr, wB, 1, &o[2]);
  sim4h_rt(xr, wC, 2, &o[4]);
  sim7(xr, wD, &o[6]);

  float* op = out + (size_t)b * 9;
#pragma unroll
  for (int i = 0; i < 9; ++i) op[i] = o[i];
}

// ---------------- launch ----------------------------------------------------

extern "C" void kernel_launch(void* const* d_in, const int* in_sizes, int n_in,
                              void* d_out, int out_size, void* d_ws, size_t ws_size,
                              hipStream_t stream) {
  const float* x  = (const float*)d_in[0];
  const float* wA = (const float*)d_in[1];
  const float* wB = (const float*)d_in[2];
  const float* wC = (const float*)d_in[3];
  const float* wD = (const float*)d_in[4];
  float* out = (float*)d_out;
  const int B = in_sizes[0] / 56;
  const int threads = 256;

  const int blocks = (B + threads - 1) / threads;
  k_all<<<blocks, threads, 0, stream>>>(x, wA, wB, wC, wD, out, B);
}

// Round 17
// 129.876 us; speedup vs baseline: 1.0805x; 1.0316x over previous
//
#include <hip/hip_runtime.h>
#include <hip/hip_fp16.h>

// Batched quantum-circuit sim — R12 configuration VERBATIM: the empirical
// optimum across 17 measured rounds (66.4us dispatch; WRITE 4.6MB = exact
// output bytes; zero bank conflicts; VGPR 120 honest, no spill).
// Structure: one thread = one element, all four sims; ABC state in vreg16,
// 7q state in two vreg64 SSA tuples (only spill-free wide-state form);
// point-of-use sincos; rolled depth loop; single writer per output row;
// launch_bounds(256,2) — loose bounds (any tighter budget wholesale-spills
// the state tuple: R10/R11/R14/R16).
// Why no further changes: occupancy is hard-capped at 8 waves/CU for the
// 65-128 VGPR class (the 128-amp state makes this class intrinsic); all
// instruction-count restructurings (R14 arrays, R14/15 unroll, R16
// noinline) regressed via spill or I-footprint. VALU-issue floor ~46us;
// the ~20us latency residue needs >2 waves/SIMD, structurally unavailable.

#define DEVINL __device__ __forceinline__

typedef _Float16 hv2 __attribute__((ext_vector_type(2)));
typedef unsigned int u32;
typedef u32 vreg16 __attribute__((ext_vector_type(16)));
typedef u32 vreg64 __attribute__((ext_vector_type(64)));

struct C2 { __half2 rr, mp; };  // complex const (r,i): rr=(r,r), mp=(-i,+i)

DEVINL C2 mkc(float re, float im) {
  C2 c; c.rr = __floats2half2_rn(re, re); c.mp = __floats2half2_rn(-im, im); return c;
}
DEVINL __half2 mkamp(float re, float im) { return __floats2half2_rn(re, im); }
DEVINL __half2 swap2(__half2 v) { return __lowhigh2highlow(v); }
// (const u) * (amp v):  (r*vr - i*vi, r*vi + i*vr)
DEVINL __half2 cmulc(C2 u, __half2 v) { return __hfma2(u.rr, v, __hmul2(u.mp, swap2(v))); }

DEVINL float ampsq(__half2 v, float acc) {
#if __has_builtin(__builtin_amdgcn_fdot2)
  return __builtin_amdgcn_fdot2(__builtin_bit_cast(hv2, v), __builtin_bit_cast(hv2, v), acc, false);
#else
  float2 f = __half22float2(v);
  return fmaf(f.x, f.x, fmaf(f.y, f.y, acc));
#endif
}

constexpr int parc(int x) { x ^= x >> 4; x ^= x >> 2; x ^= x >> 1; return x & 1; }

struct c32 { float x, y; };
DEVINL c32 cmulf(c32 a, c32 b) { return { a.x*b.x - a.y*b.y, a.x*b.y + a.y*b.x }; }

// ---- SSA state accessors ----------------------------------------------------
template<class VT>
DEVINL __half2 vget(const VT& A, int i) { return __builtin_bit_cast(__half2, (u32)A[i]); }
template<class VT>
DEVINL void vset(VT& A, int i, __half2 v) { A[i] = __builtin_bit_cast(u32, v); }

// 128-amp state = two vreg64 tuples; index folds to constant after unroll.
struct S128 { vreg64 lo, hi; };
DEVINL __half2 vget(const S128& A, int i) {
  u32 u = (i < 64) ? (u32)A.lo[i] : (u32)A.hi[i - 64];
  return __builtin_bit_cast(__half2, u);
}
DEVINL void vset(S128& A, int i, __half2 v) {
  u32 u = __builtin_bit_cast(u32, v);
  if (i < 64) A.lo[i] = u; else A.hi[i - 64] = u;
}

// ---------------- generic gates (qubit W of N; mask = 1<<(N-1-W)) -----------

template<int N, int W, class VT>
DEVINL void g_ry(VT& A, __half2 c2, __half2 s2, __half2 ns2) {
  constexpr int M = 1 << (N - 1 - W);
#pragma unroll
  for (int i = 0; i < (1 << N); ++i) if (!(i & M)) {
    const int j = i | M;
    __half2 v0 = vget(A, i), v1 = vget(A, j);
    vset(A, i, __hfma2(c2, v0, __hmul2(ns2, v1)));
    vset(A, j, __hfma2(c2, v1, __hmul2(s2, v0)));
  }
}

template<int N, int W, class VT>
DEVINL void g_u2(VT& A, C2 u00, C2 u01, C2 u10, C2 u11) {
  constexpr int M = 1 << (N - 1 - W);
#pragma unroll
  for (int i = 0; i < (1 << N); ++i) if (!(i & M)) {
    const int j = i | M;
    __half2 v0 = vget(A, i), v1 = vget(A, j), v0s = swap2(v0), v1s = swap2(v1);
    vset(A, i, __hfma2(u00.rr, v0, __hfma2(u00.mp, v0s, __hfma2(u01.rr, v1, __hmul2(u01.mp, v1s)))));
    vset(A, j, __hfma2(u10.rr, v0, __hfma2(u10.mp, v0s, __hfma2(u11.rr, v1, __hmul2(u11.mp, v1s)))));
  }
}

template<int N, int C, int T, class VT>
DEVINL void g_cnot(VT& A) {
  constexpr int CM = 1 << (N - 1 - C), TM = 1 << (N - 1 - T);
#pragma unroll
  for (int i = 0; i < (1 << N); ++i) if ((i & CM) && !(i & TM)) {
    const int j = i | TM;
    __half2 t = vget(A, i); vset(A, i, vget(A, j)); vset(A, j, t);
  }
}

template<int N, int K, class VT>
DEVINL void chain_cnot(VT& A) {
  if constexpr (K < N - 1) { g_cnot<N, K, K + 1>(A); chain_cnot<N, K + 1>(A); }
}

// ---------------- per-qubit coefficients (f32) ------------------------------
// forward: u = Rz(phi)Ry(pt)Rx(eta)|0>;  reverse merged: U = Rx(phi)Ry(pt)Rz(eta)

DEVINL void mk_u01(float ce, float se, float cp, float sp, float cf, float sf,
                   c32& u0, c32& u1) {
  u0 = cmulf({cf, -sf}, {cp * ce, sp * se});
  u1 = cmulf({cf,  sf}, {sp * ce, -cp * se});
}

DEVINL void mk_U(float ce, float se, float cp, float sp, float cf, float sf,
                 C2& U00, C2& U01, C2& U10, C2& U11) {
  c32 z = {ce, -se}, zb = {ce, se};
  c32 A = cmulf({cf * cp, -sf * sp}, z);
  c32 T = cmulf({cf * sp,  sf * cp}, zb);
  c32 Cc = cmulf({cf * sp, -sf * cp}, z);
  c32 D = cmulf({cf * cp,  sf * sp}, zb);
  U00 = mkc(A.x, A.y); U01 = mkc(-T.x, -T.y); U10 = mkc(Cc.x, Cc.y); U11 = mkc(D.x, D.y);
}

// per-qubit sincos loader (eta_i<0 -> eta=0)
DEVINL void load_sc(const float* __restrict__ xr, int eta_i, int pt_i, int phi_i,
                    float& ce, float& se, float& cp, float& sp, float& cf, float& sf) {
  float e = (eta_i < 0) ? 0.f : xr[eta_i];
  __sincosf(0.5f * e, &se, &ce);
  __sincosf(0.5f * xr[pt_i], &sp, &cp);
  __sincosf(0.5f * xr[phi_i], &sf, &cf);
}

// product state build by doubling (A[0] must be (1,0) on entry).
// step M's qubit lands at bit (N-1-M). CF(M,u0,u1) supplies the column.
template<int N, int M, class VT, class CF>
DEVINL void build_rec(VT& A, CF cf) {
  if constexpr (M < N) {
    c32 u0, u1; cf(M, u0, u1);
    C2 c0 = mkc(u0.x, u0.y), c1 = mkc(u1.x, u1.y);
#pragma unroll
    for (int j = (1 << M) - 1; j >= 0; --j) {
      __half2 s = vget(A, j);
      vset(A, 2 * j,     cmulc(c0, s));
      vset(A, 2 * j + 1, cmulc(c1, s));
    }
    build_rec<N, M + 1>(A, cf);
  }
}

template<int N, int K, class VT, class CF>
DEVINL void usweep_rec(VT& A, CF cf) {
  if constexpr (K < N) {
    C2 U00, U01, U10, U11;
    cf(K, U00, U01, U10, U11);
    g_u2<N, K>(A, U00, U01, U10, U11);
    usweep_rec<N, K + 1>(A, cf);
  }
}

template<int N, int K, class VT, class CF>
DEVINL void ry_rec(VT& A, CF cf) {
  if constexpr (K < N) {
    __half2 c2, s2, ns2;
    cf(K, c2, s2, ns2);
    g_ry<N, K>(A, c2, s2, ns2);
    ry_rec<N, K + 1>(A, cf);
  }
}

// ---------------- 4-qubit block I (verified math, SSA state) ----------------

template<int I>
DEVINL void sim4h(const float* __restrict__ xr, const float* __restrict__ w, float* z) {
  constexpr int PT[3][4]  = {{5, 4, 35, 34}, {3, 33, 31, 2}, {28, 32, 15, 16}};
  constexpr int ETA[3][4] = {{9, 8, 45, 44}, {7, 43, 41, 6}, {38, 42, 19, 20}};
  constexpr int PHI[3][4] = {{13, 12, 55, 54}, {11, 53, 51, 10}, {48, 52, 23, 24}};
  vreg16 A;
  vset(A, 0, mkamp(1.f, 0.f));
  build_rec<4, 0>(A, [&](int M, c32& u0, c32& u1) {
    float ce, se, cp, sp, cf, sf;
    load_sc(xr, ETA[I][M], PT[I][M], PHI[I][M], ce, se, cp, sp, cf, sf);
    mk_u01(ce, se, cp, sp, cf, sf, u0, u1);
  });
  chain_cnot<4, 0>(A);
  usweep_rec<4, 0>(A, [&](int K, C2& U00, C2& U01, C2& U10, C2& U11) {
    float ce, se, cp, sp, cf, sf;
    load_sc(xr, ETA[I][K], PT[I][K], PHI[I][K], ce, se, cp, sp, cf, sf);
    mk_U(ce, se, cp, sp, cf, sf, U00, U01, U10, U11);
  });

  // t->l CNOT block == flip q0,q1 (mask 12) iff parity(b2,b3) (i&3)
#pragma unroll
  for (int i = 0; i < 16; ++i)
    if (parc(i & 3) && !(i & 8)) {
      __half2 t = vget(A, i); vset(A, i, vget(A, i ^ 12)); vset(A, i ^ 12, t);
    }

  ry_rec<4, 0>(A, [&](int K, __half2& c2, __half2& s2, __half2& ns2) {
    float sv, cv; __sincosf(0.5f * w[K], &sv, &cv);
    c2 = __floats2half2_rn(cv, cv);
    s2 = __floats2half2_rn(sv, sv);
    ns2 = __floats2half2_rn(-sv, -sv);
  });

  // l->t CNOT block == flip q2,q3 (mask 3) iff parity(b0,b1) (i&12)
#pragma unroll
  for (int i = 0; i < 16; ++i)
    if (parc(i & 12) && !(i & 2)) {
      __half2 t = vget(A, i); vset(A, i, vget(A, i ^ 3)); vset(A, i ^ 3, t);
    }

  float cls[4];
#pragma unroll
  for (int c = 0; c < 4; ++c) cls[c] = 0.f;
#pragma unroll
  for (int i = 0; i < 16; ++i) cls[i & 3] = ampsq(vget(A, i), cls[i & 3]);
  float z0 = 0.f, z1 = 0.f;
#pragma unroll
  for (int c = 0; c < 4; ++c) {
    z0 += (c & 2) ? -cls[c] : cls[c];
    z1 += (c & 1) ? -cls[c] : cls[c];
  }
  z[0] = z0; z[1] = z1;
}

// ---------------- 7-qubit block (verified math, S128 SSA state) -------------
// qubit k at bit 6-k. latent=(0..3) trash=(4,5,6) depth=4.

DEVINL void sim7(const float* __restrict__ xr, const float* __restrict__ wD,
                 float* z) {
  constexpr int PT[7]  = {0, 14, 30, 26, 29, 27, 17};
  constexpr int ETA[7] = {-1, 18, 40, 36, 39, 37, 21};  // -1 -> zeros (None)
  constexpr int PHI[7] = {1, 22, 50, 46, 49, 47, 25};

  S128 A;
  vset(A, 0, mkamp(1.f, 0.f));
  build_rec<7, 0>(A, [&](int M, c32& u0, c32& u1) {
    float ce, se, cp, sp, cf, sf;
    load_sc(xr, ETA[M], PT[M], PHI[M], ce, se, cp, sp, cf, sf);
    mk_u01(ce, se, cp, sp, cf, sf, u0, u1);
  });
  chain_cnot<7, 0>(A);
  usweep_rec<7, 0>(A, [&](int K, C2& U00, C2& U01, C2& U10, C2& U11) {
    float ce, se, cp, sp, cf, sf;
    load_sc(xr, ETA[K], PT[K], PHI[K], ce, se, cp, sp, cf, sf);
    mk_U(ce, se, cp, sp, cf, sf, U00, U01, U10, U11);
  });

  // depth loop kept rolled: body stays in L1I
#pragma unroll 1
  for (int d = 0; d < 4; ++d) {
    // t->l block == flip q0..q3 (mask 0x78) iff parity(q4,q5,q6) (i&7)
#pragma unroll
    for (int i = 0; i < 128; ++i)
      if (parc(i & 7) && !(i & 64)) {
        __half2 t = vget(A, i); vset(A, i, vget(A, i ^ 0x78)); vset(A, i ^ 0x78, t);
      }

    ry_rec<7, 0>(A, [&](int K, __half2& c2, __half2& s2, __half2& ns2) {
      float sv, cv; __sincosf(0.5f * wD[7 * d + K], &sv, &cv);
      c2 = __floats2half2_rn(cv, cv);
      s2 = __floats2half2_rn(sv, sv);
      ns2 = __floats2half2_rn(-sv, -sv);
    });

    // l->t block == flip q4..q6 (mask 7) iff parity(q0..q3) (i&0x78)
#pragma unroll
    for (int i = 0; i < 128; ++i)
      if (parc(i & 0x78) && !(i & 4)) {
        __half2 t = vget(A, i); vset(A, i, vget(A, i ^ 7)); vset(A, i ^ 7, t);
      }
  }

  float cls[8];
#pragma unroll
  for (int c = 0; c < 8; ++c) cls[c] = 0.f;
#pragma unroll
  for (int i = 0; i < 128; ++i) cls[i & 7] = ampsq(vget(A, i), cls[i & 7]);
  float z4 = 0.f, z5 = 0.f, z6 = 0.f;
#pragma unroll
  for (int c = 0; c < 8; ++c) {
    z4 += (c & 4) ? -cls[c] : cls[c];
    z5 += (c & 2) ? -cls[c] : cls[c];
    z6 += (c & 1) ? -cls[c] : cls[c];
  }
  z[0] = z4; z[1] = z5; z[2] = z6;
}

// ---------------- fused kernel: one thread per element ----------------------

__global__ void __launch_bounds__(256, 2)
k_all(const float* __restrict__ x,
      const float* __restrict__ wA, const float* __restrict__ wB,
      const float* __restrict__ wC, const float* __restrict__ wD,
      float* __restrict__ out, int B) {
  const int b = blockIdx.x * 256 + threadIdx.x;
  if (b >= B) return;
  const float* xr = x + (size_t)b * 56;

  float o[9];
  // ABC first: vreg16 state is dead before the 128-reg 7q state allocates.
  sim4h<0>(xr, wA, &o[0]);
  sim4h<1>(xr, wB, &o[2]);
  sim4h<2>(xr, wC, &o[4]);
  sim7(xr, wD, &o[6]);

  float* op = out + (size_t)b * 9;
#pragma unroll
  for (int i = 0; i < 9; ++i) op[i] = o[i];
}

// ---------------- launch ----------------------------------------------------

extern "C" void kernel_launch(void* const* d_in, const int* in_sizes, int n_in,
                              void* d_out, int out_size, void* d_ws, size_t ws_size,
                              hipStream_t stream) {
  const float* x  = (const float*)d_in[0];
  const float* wA = (const float*)d_in[1];
  const float* wB = (const float*)d_in[2];
  const float* wC = (const float*)d_in[3];
  const float* wD = (const float*)d_in[4];
  float* out = (float*)d_out;
  const int B = in_sizes[0] / 56;
  const int threads = 256;

  const int blocks = (B + threads - 1) / threads;
  k_all<<<blocks, threads, 0, stream>>>(x, wA, wB, wC, wD, out, B);
}